// Round 9
// baseline (466.368 us; speedup 1.0000x reference)
//
#include <hip/hip_runtime.h>
#include <hip/hip_bf16.h>

#define V_SIZE 32000
#define SEQ 64
#define BATCH 64
#define EMB 32
#define HID 16
#define NROWS (SEQ * BATCH)   // 4096
#define V4 (V_SIZE / 4)       // 8000 float4 columns
#define STRIPS 32             // 32 strips * 256 f4-cols = 8192 >= 8000
#define CHUNKS 64
#define ROWS_W (NROWS / CHUNKS)   // 64 rows per chunk
#define NSLOTS (STRIPS * 4)       // per-wave partial slots per row
#define RGROUP 8                  // rows per inner group in k_write
#define REPS 4                    // DIAGNOSTIC: internal repeat so k_write tops profile

typedef float f32x4 __attribute__((ext_vector_type(4)));

// ---------------------------------------------------------------------------
// Kernel A: h_table[r][j] = sigmoid( lookup[idx[r]] . wx[:,j] + (h0 @ wh)[j] )
// ---------------------------------------------------------------------------
__global__ __launch_bounds__(256) void k_htable(
    const int* __restrict__ idx, const float* __restrict__ lookup,
    const float* __restrict__ wx, const float* __restrict__ wh,
    const float* __restrict__ h0, float* __restrict__ h_table)
{
    int r = blockIdx.x * 256 + threadIdx.x;
    if (r >= NROWS) return;

    float acc[HID];
    #pragma unroll
    for (int j = 0; j < HID; ++j) acc[j] = 0.f;

    #pragma unroll
    for (int i = 0; i < HID; ++i) {
        float h0i = h0[i];
        #pragma unroll
        for (int j = 0; j < HID; ++j) acc[j] += h0i * wh[i * HID + j];
    }

    int tok = idx[r];
    const float* xrow = lookup + (long)tok * EMB;
    #pragma unroll
    for (int e = 0; e < EMB; ++e) {
        float x = xrow[e];
        #pragma unroll
        for (int j = 0; j < HID; ++j) acc[j] += x * wx[e * HID + j];
    }

    #pragma unroll
    for (int j = 0; j < HID; ++j)
        h_table[r * HID + j] = 1.f / (1.f + __expf(-acc[j]));
}

// ---------------------------------------------------------------------------
// Kernel B: per-wave partial exp-sums, 4-row groups for ILP.
// (BIT-IDENTICAL to Round 7; measured at ~68 µs via Round-8 ablation.)
// ---------------------------------------------------------------------------
__global__ __launch_bounds__(256) void k_expsum(
    const float* __restrict__ h_table, const float* __restrict__ wo,
    float* __restrict__ partial)
{
    const int tid = threadIdx.x;
    const int strip = blockIdx.x & (STRIPS - 1);
    const int chunk = blockIdx.x / STRIPS;
    const int v4 = strip * 256 + tid;
    const bool act = v4 < V4;
    const int r0 = chunk * ROWS_W;
    const int wave = tid >> 6;
    const int lane = tid & 63;

    const f32x4* wo4 = reinterpret_cast<const f32x4*>(wo);
    f32x4 w[HID];
    #pragma unroll
    for (int j = 0; j < HID; ++j) {
        if (act) w[j] = wo4[j * V4 + v4];
        else     w[j] = (f32x4){0.f, 0.f, 0.f, 0.f};
    }

    float* slot = partial + (size_t)(strip * 4 + wave) * NROWS;

    for (int rr = r0; rr < r0 + ROWS_W; rr += 4) {
        f32x4 acc[4];
        #pragma unroll
        for (int i = 0; i < 4; ++i) acc[i] = (f32x4){0.f, 0.f, 0.f, 0.f};

        #pragma unroll
        for (int q = 0; q < 4; ++q) {
            f32x4 h4[4];
            #pragma unroll
            for (int i = 0; i < 4; ++i)
                h4[i] = *reinterpret_cast<const f32x4*>(h_table + (rr + i) * HID + q * 4);
            #pragma unroll
            for (int i = 0; i < 4; ++i) {
                acc[i] += h4[i].x * w[q * 4 + 0];
                acc[i] += h4[i].y * w[q * 4 + 1];
                acc[i] += h4[i].z * w[q * 4 + 2];
                acc[i] += h4[i].w * w[q * 4 + 3];
            }
        }

        float s[4];
        #pragma unroll
        for (int i = 0; i < 4; ++i) {
            float e = __expf(acc[i].x) + __expf(acc[i].y) +
                      __expf(acc[i].z) + __expf(acc[i].w);
            s[i] = act ? e : 0.f;
        }

        #pragma unroll
        for (int off = 32; off >= 1; off >>= 1) {
            #pragma unroll
            for (int i = 0; i < 4; ++i)
                s[i] += __shfl_xor(s[i], off, 64);
        }

        if (lane == 0) {
            f32x4 o = {s[0], s[1], s[2], s[3]};
            *reinterpret_cast<f32x4*>(slot + rr) = o;
        }
    }
}

// ---------------------------------------------------------------------------
// Kernel B2: lse[r] = log( sum over 128 slots of partial[slot][r] )
// ---------------------------------------------------------------------------
__global__ __launch_bounds__(256) void k_reduce(
    const float* __restrict__ partial, float* __restrict__ lse)
{
    int r = blockIdx.x * 256 + threadIdx.x;
    if (r >= NROWS) return;
    float s = 0.f;
    #pragma unroll
    for (int k = 0; k < NSLOTS; ++k)
        s += partial[(size_t)k * NROWS + r];
    lse[r] = __logf(s);
}

// ---------------------------------------------------------------------------
// Kernel C: 8-row groups (8 independent acc sets -> store-data registers are
// not reused until a full FMA block later, removing any vmcnt-on-store stall).
// REPS=4 internal repeat (idempotent, identical values) is DIAGNOSTIC ONLY:
// makes this dispatch ~400+ us so it tops the profile with full counters.
// ---------------------------------------------------------------------------
__global__ __launch_bounds__(256) void k_write(
    const float* __restrict__ h_table, const float* __restrict__ wo,
    const float* __restrict__ lse, float* __restrict__ out)
{
    const int tid = threadIdx.x;
    const int strip = blockIdx.x & (STRIPS - 1);
    const int chunk = blockIdx.x / STRIPS;
    const int v4 = strip * 256 + tid;
    const bool act = v4 < V4;
    const int r0 = chunk * ROWS_W;

    const f32x4* wo4 = reinterpret_cast<const f32x4*>(wo);
    f32x4 w[HID];
    #pragma unroll
    for (int j = 0; j < HID; ++j) {
        if (act) w[j] = wo4[j * V4 + v4];
        else     w[j] = (f32x4){0.f, 0.f, 0.f, 0.f};
    }

    f32x4* out4 = reinterpret_cast<f32x4*>(out);

    #pragma unroll 1
    for (int rep = 0; rep < REPS; ++rep) {
        for (int rr = r0; rr < r0 + ROWS_W; rr += RGROUP) {
            f32x4 acc[RGROUP];
            #pragma unroll
            for (int i = 0; i < RGROUP; ++i) acc[i] = (f32x4){0.f, 0.f, 0.f, 0.f};

            #pragma unroll
            for (int q = 0; q < 4; ++q) {
                f32x4 h4[RGROUP];
                #pragma unroll
                for (int i = 0; i < RGROUP; ++i)
                    h4[i] = *reinterpret_cast<const f32x4*>(h_table + (rr + i) * HID + q * 4);
                #pragma unroll
                for (int i = 0; i < RGROUP; ++i) {
                    acc[i] += h4[i].x * w[q * 4 + 0];
                    acc[i] += h4[i].y * w[q * 4 + 1];
                    acc[i] += h4[i].z * w[q * 4 + 2];
                    acc[i] += h4[i].w * w[q * 4 + 3];
                }
            }

            const f32x4 ls0 = *reinterpret_cast<const f32x4*>(lse + rr);
            const f32x4 ls1 = *reinterpret_cast<const f32x4*>(lse + rr + 4);

            if (act) {
                #pragma unroll
                for (int i = 0; i < RGROUP; ++i) {
                    float l = (i < 4) ? ls0[i & 3] : ls1[i & 3];
                    f32x4 o = acc[i] - l;
                    out4[(long)(rr + i) * V4 + v4] = o;
                }
            }
        }
    }
}

extern "C" void kernel_launch(void* const* d_in, const int* in_sizes, int n_in,
                              void* d_out, int out_size, void* d_ws, size_t ws_size,
                              hipStream_t stream) {
    const int*   idx    = (const int*)d_in[0];
    const float* lookup = (const float*)d_in[1];
    const float* wx     = (const float*)d_in[2];
    const float* wh     = (const float*)d_in[3];
    const float* wo     = (const float*)d_in[4];
    const float* h0     = (const float*)d_in[5];
    float* out = (float*)d_out;

    float* h_table = (float*)d_ws;                    // 4096*16 floats (256 KB)
    float* lse     = h_table + NROWS * HID;           // 4096 floats
    float* partial = lse + NROWS;                     // 128*4096 floats (2 MB)

    k_htable<<<NROWS / 256, 256, 0, stream>>>(idx, lookup, wx, wh, h0, h_table);
    k_expsum<<<STRIPS * CHUNKS, 256, 0, stream>>>(h_table, wo, partial);
    k_reduce<<<NROWS / 256, 256, 0, stream>>>(partial, lse);
    k_write<<<STRIPS * CHUNKS, 256, 0, stream>>>(h_table, wo, lse, out);
}

// Round 10
// 251.426 us; speedup vs baseline: 1.8549x; 1.8549x over previous
//
#include <hip/hip_runtime.h>
#include <hip/hip_bf16.h>

#define V_SIZE 32000
#define SEQ 64
#define BATCH 64
#define EMB 32
#define HID 16
#define NROWS (SEQ * BATCH)   // 4096
#define V4 (V_SIZE / 4)       // 8000 float4 columns
#define STRIPS 32             // k_write: 32 strips * 256 f4-cols = 8192 >= 8000
#define CHUNKS 64
#define ROWS_W (NROWS / CHUNKS)   // 64 rows per chunk
#define RGROUP 8                  // rows per inner group in k_write
#define XSTRIPS 64                // k_expsum: v4 strips (8000/64 = 125 per wave)
#define XV4 (V4 / XSTRIPS)        // 125
#define NSLOTS XSTRIPS            // partial slots per row

typedef float f32x4 __attribute__((ext_vector_type(4)));

// ---------------------------------------------------------------------------
// Kernel A: h_table[r][j] = sigmoid( lookup[idx[r]] . wx[:,j] + (h0 @ wh)[j] )
// ---------------------------------------------------------------------------
__global__ __launch_bounds__(256) void k_htable(
    const int* __restrict__ idx, const float* __restrict__ lookup,
    const float* __restrict__ wx, const float* __restrict__ wh,
    const float* __restrict__ h0, float* __restrict__ h_table)
{
    int r = blockIdx.x * 256 + threadIdx.x;
    if (r >= NROWS) return;

    float acc[HID];
    #pragma unroll
    for (int j = 0; j < HID; ++j) acc[j] = 0.f;

    #pragma unroll
    for (int i = 0; i < HID; ++i) {
        float h0i = h0[i];
        #pragma unroll
        for (int j = 0; j < HID; ++j) acc[j] += h0i * wh[i * HID + j];
    }

    int tok = idx[r];
    const float* xrow = lookup + (long)tok * EMB;
    #pragma unroll
    for (int e = 0; e < EMB; ++e) {
        float x = xrow[e];
        #pragma unroll
        for (int j = 0; j < HID; ++j) acc[j] += x * wx[e * HID + j];
    }

    #pragma unroll
    for (int j = 0; j < HID; ++j)
        h_table[r * HID + j] = 1.f / (1.f + __expf(-acc[j]));
}

// ---------------------------------------------------------------------------
// Kernel B (lane = row): wave = 64 lanes = 64 rows. Each wave sweeps a 125-
// wide v4 strip. Wo loads are wave-uniform (scalar path / broadcast); h lives
// in 16 VGPRs per lane; each lane accumulates its own row's exp-sum.
// NO cross-lane ops in the inner loop. One coalesced store per wave at end.
// Deterministic: fixed per-lane sweep order, fixed slot per (strip,row).
// ---------------------------------------------------------------------------
__global__ __launch_bounds__(256) void k_expsum(
    const float* __restrict__ h_table, const float* __restrict__ wo,
    float* __restrict__ partial)
{
    const int lane = threadIdx.x & 63;
    const int wid  = __builtin_amdgcn_readfirstlane(threadIdx.x >> 6);
    const int g = blockIdx.x * 4 + wid;   // global wave id, 0..4095
    const int group = g & 63;             // row-group (waves in a block share strip)
    const int strip = g >> 6;             // 0..63
    const int row = group * 64 + lane;

    // own row's h in registers (16 VGPR)
    f32x4 h[4];
    #pragma unroll
    for (int q = 0; q < 4; ++q)
        h[q] = *reinterpret_cast<const f32x4*>(h_table + row * HID + q * 4);

    const f32x4* wo4 = reinterpret_cast<const f32x4*>(wo);
    float acc = 0.f;

    const int v0 = strip * XV4;
    for (int v = v0; v < v0 + XV4; ++v) {
        f32x4 lv0 = {0.f, 0.f, 0.f, 0.f};
        f32x4 lv1 = {0.f, 0.f, 0.f, 0.f};
        #pragma unroll
        for (int j = 0; j < HID; j += 2) {
            f32x4 w0 = wo4[(size_t)j * V4 + v];        // wave-uniform address
            f32x4 w1 = wo4[(size_t)(j + 1) * V4 + v];
            lv0 += h[j >> 2][j & 3] * w0;
            lv1 += h[(j + 1) >> 2][(j + 1) & 3] * w1;
        }
        f32x4 lv = lv0 + lv1;
        acc += __expf(lv.x) + __expf(lv.y) + __expf(lv.z) + __expf(lv.w);
    }

    partial[(size_t)strip * NROWS + row] = acc;   // coalesced 64x4B
}

// ---------------------------------------------------------------------------
// Kernel B2: lse[r] = log( sum over 64 slots of partial[slot][r] )
// Fixed summation order -> deterministic.
// ---------------------------------------------------------------------------
__global__ __launch_bounds__(256) void k_reduce(
    const float* __restrict__ partial, float* __restrict__ lse)
{
    int r = blockIdx.x * 256 + threadIdx.x;
    if (r >= NROWS) return;
    float s = 0.f;
    #pragma unroll
    for (int k = 0; k < NSLOTS; ++k)
        s += partial[(size_t)k * NROWS + r];
    lse[r] = __logf(s);
}

// ---------------------------------------------------------------------------
// Kernel C: lanes own v4-columns; Wo in registers; 8-row groups (R9 structure,
// measured 90 us/pass @ 5.84 TB/s). REPS removed.
// ---------------------------------------------------------------------------
__global__ __launch_bounds__(256) void k_write(
    const float* __restrict__ h_table, const float* __restrict__ wo,
    const float* __restrict__ lse, float* __restrict__ out)
{
    const int tid = threadIdx.x;
    const int strip = blockIdx.x & (STRIPS - 1);
    const int chunk = blockIdx.x / STRIPS;
    const int v4 = strip * 256 + tid;
    const bool act = v4 < V4;
    const int r0 = chunk * ROWS_W;

    const f32x4* wo4 = reinterpret_cast<const f32x4*>(wo);
    f32x4 w[HID];
    #pragma unroll
    for (int j = 0; j < HID; ++j) {
        if (act) w[j] = wo4[j * V4 + v4];
        else     w[j] = (f32x4){0.f, 0.f, 0.f, 0.f};
    }

    f32x4* out4 = reinterpret_cast<f32x4*>(out);

    for (int rr = r0; rr < r0 + ROWS_W; rr += RGROUP) {
        f32x4 acc[RGROUP];
        #pragma unroll
        for (int i = 0; i < RGROUP; ++i) acc[i] = (f32x4){0.f, 0.f, 0.f, 0.f};

        #pragma unroll
        for (int q = 0; q < 4; ++q) {
            f32x4 h4[RGROUP];
            #pragma unroll
            for (int i = 0; i < RGROUP; ++i)
                h4[i] = *reinterpret_cast<const f32x4*>(h_table + (rr + i) * HID + q * 4);
            #pragma unroll
            for (int i = 0; i < RGROUP; ++i) {
                acc[i] += h4[i].x * w[q * 4 + 0];
                acc[i] += h4[i].y * w[q * 4 + 1];
                acc[i] += h4[i].z * w[q * 4 + 2];
                acc[i] += h4[i].w * w[q * 4 + 3];
            }
        }

        const f32x4 ls0 = *reinterpret_cast<const f32x4*>(lse + rr);
        const f32x4 ls1 = *reinterpret_cast<const f32x4*>(lse + rr + 4);

        if (act) {
            #pragma unroll
            for (int i = 0; i < RGROUP; ++i) {
                float l = (i < 4) ? ls0[i & 3] : ls1[i & 3];
                f32x4 o = acc[i] - l;
                out4[(long)(rr + i) * V4 + v4] = o;
            }
        }
    }
}

extern "C" void kernel_launch(void* const* d_in, const int* in_sizes, int n_in,
                              void* d_out, int out_size, void* d_ws, size_t ws_size,
                              hipStream_t stream) {
    const int*   idx    = (const int*)d_in[0];
    const float* lookup = (const float*)d_in[1];
    const float* wx     = (const float*)d_in[2];
    const float* wh     = (const float*)d_in[3];
    const float* wo     = (const float*)d_in[4];
    const float* h0     = (const float*)d_in[5];
    float* out = (float*)d_out;

    float* h_table = (float*)d_ws;                    // 4096*16 floats (256 KB)
    float* lse     = h_table + NROWS * HID;           // 4096 floats
    float* partial = lse + NROWS;                     // 64*4096 floats (1 MB)

    k_htable<<<NROWS / 256, 256, 0, stream>>>(idx, lookup, wx, wh, h0, h_table);
    k_expsum<<<(XSTRIPS * 64) / 4, 256, 0, stream>>>(h_table, wo, partial);
    k_reduce<<<NROWS / 256, 256, 0, stream>>>(partial, lse);
    k_write<<<STRIPS * CHUNKS, 256, 0, stream>>>(h_table, wo, lse, out);
}

// Round 11
// 161.344 us; speedup vs baseline: 2.8905x; 1.5583x over previous
//
#include <hip/hip_runtime.h>
#include <hip/hip_bf16.h>

#define V_SIZE 32000
#define SEQ 64
#define BATCH 64
#define EMB 32
#define HID 16
#define NROWS (SEQ * BATCH)   // 4096
#define V4 (V_SIZE / 4)       // 8000 float4 columns
#define STRIPS 32             // k_write: 32 strips * 256 f4-cols
#define CHUNKS 64
#define ROWS_W (NROWS / CHUNKS)   // 64 rows per chunk
#define RGROUP 8                  // rows per inner group in k_write
#define NRB (NROWS / 16)          // 256 row-blocks (MFMA M-tiles)
#define NTILES (V_SIZE / 16)      // 2000 col-tiles (MFMA N-tiles)
#define XSTRIPS 50                // expsum strips
#define TPW (NTILES / XSTRIPS)    // 40 tiles per wave
#define NSLOTS XSTRIPS

typedef float f32x4 __attribute__((ext_vector_type(4)));
typedef short short8 __attribute__((ext_vector_type(8)));

__device__ inline short bf16_rne(float x) {
    unsigned u = __builtin_bit_cast(unsigned, x);
    unsigned r = u + 0x7FFFu + ((u >> 16) & 1u);
    return (short)(r >> 16);
}

// ---------------------------------------------------------------------------
// Kernel A: h_table[r][j] = sigmoid(lookup[idx[r]].wx[:,j] + (h0@wh)[j])
// Also emits bf16 A-fragments for the MFMA expsum:
//   a_frag[rb][lane][j] holds A[row=lane&15][k=(lane>>4)*8+j], zero for k>=16.
// ---------------------------------------------------------------------------
__global__ __launch_bounds__(256) void k_htable(
    const int* __restrict__ idx, const float* __restrict__ lookup,
    const float* __restrict__ wx, const float* __restrict__ wh,
    const float* __restrict__ h0, float* __restrict__ h_table,
    short* __restrict__ a_frag)
{
    int r = blockIdx.x * 256 + threadIdx.x;
    if (r >= NROWS) return;

    float acc[HID];
    #pragma unroll
    for (int j = 0; j < HID; ++j) acc[j] = 0.f;

    #pragma unroll
    for (int i = 0; i < HID; ++i) {
        float h0i = h0[i];
        #pragma unroll
        for (int j = 0; j < HID; ++j) acc[j] += h0i * wh[i * HID + j];
    }

    int tok = idx[r];
    const float* xrow = lookup + (long)tok * EMB;
    #pragma unroll
    for (int e = 0; e < EMB; ++e) {
        float x = xrow[e];
        #pragma unroll
        for (int j = 0; j < HID; ++j) acc[j] += x * wx[e * HID + j];
    }

    float h[HID];
    #pragma unroll
    for (int j = 0; j < HID; ++j) {
        h[j] = 1.f / (1.f + __expf(-acc[j]));
        h_table[r * HID + j] = h[j];
    }

    // A-fragments (16x16x32 bf16, K padded 16->32)
    const int rb = r >> 4;
    const int m  = r & 15;
    short8 lo, hi, zz;
    #pragma unroll
    for (int j = 0; j < 8; ++j) {
        lo[j] = bf16_rne(h[j]);
        hi[j] = bf16_rne(h[j + 8]);
        zz[j] = 0;
    }
    short8* af = reinterpret_cast<short8*>(a_frag);
    af[rb * 64 + m]      = lo;   // lanes 0..15:  k = 0..7
    af[rb * 64 + m + 16] = hi;   // lanes 16..31: k = 8..15
    af[rb * 64 + m + 32] = zz;   // lanes 32..47: k = 16..23 (pad)
    af[rb * 64 + m + 48] = zz;   // lanes 48..63: k = 24..31 (pad)
}

// ---------------------------------------------------------------------------
// Kernel A2: pack Wo into bf16 B-fragments.
//   b_frag[t][lane][j] holds B[k=(lane>>4)*8+j][col=t*16+(lane&15)], 0 for k>=16.
// Same slot->k convention as A, so any consistent permutation cancels.
// ---------------------------------------------------------------------------
__global__ __launch_bounds__(256) void k_wpack(
    const float* __restrict__ wo, short* __restrict__ b_frag)
{
    int gid = blockIdx.x * 256 + threadIdx.x;   // 2000*64 threads
    if (gid >= NTILES * 64) return;
    const int t = gid >> 6;
    const int l = gid & 63;
    const int col = t * 16 + (l & 15);

    short8 b;
    if (l < 32) {
        const int k0 = (l >> 4) * 8;
        #pragma unroll
        for (int j = 0; j < 8; ++j)
            b[j] = bf16_rne(wo[(size_t)(k0 + j) * V_SIZE + col]);
    } else {
        #pragma unroll
        for (int j = 0; j < 8; ++j) b[j] = 0;
    }
    reinterpret_cast<short8*>(b_frag)[gid] = b;
}

// ---------------------------------------------------------------------------
// Kernel B: MFMA exp-sum. Wave = (row-block rb, strip s); sweeps 40 col-tiles.
// Per tile: 16B b-frag load + 1 mfma_f32_16x16x32_bf16 + 4 exp + 4 add.
// C/D layout (m89-verified): col=lane&15, row=(lane>>4)*4+reg.
// One 16-lane shfl reduce per wave at the end; fixed slot -> deterministic.
// ---------------------------------------------------------------------------
__global__ __launch_bounds__(256) void k_expsum(
    const short* __restrict__ a_frag, const short* __restrict__ b_frag,
    float* __restrict__ partial)
{
    const int lane = threadIdx.x & 63;
    const int wid  = threadIdx.x >> 6;
    const int g = blockIdx.x * 4 + wid;      // 0..12799
    const int rb = g & (NRB - 1);            // 0..255
    const int strip = g >> 8;                // 0..49

    const short8* af = reinterpret_cast<const short8*>(a_frag);
    const short8* bf = reinterpret_cast<const short8*>(b_frag);

    const short8 a = af[rb * 64 + lane];

    f32x4 acc = {0.f, 0.f, 0.f, 0.f};
    const f32x4 czero = {0.f, 0.f, 0.f, 0.f};

    const int t0 = strip * TPW;
    for (int t = t0; t < t0 + TPW; ++t) {
        const short8 b = bf[t * 64 + lane];
        f32x4 d = __builtin_amdgcn_mfma_f32_16x16x32_bf16(a, b, czero, 0, 0, 0);
        acc.x += __expf(d.x);
        acc.y += __expf(d.y);
        acc.z += __expf(d.z);
        acc.w += __expf(d.w);
    }

    // reduce across the 16 column-lanes (l&15)
    #pragma unroll
    for (int off = 1; off <= 8; off <<= 1) {
        acc.x += __shfl_xor(acc.x, off, 64);
        acc.y += __shfl_xor(acc.y, off, 64);
        acc.z += __shfl_xor(acc.z, off, 64);
        acc.w += __shfl_xor(acc.w, off, 64);
    }

    if ((lane & 15) == 0) {
        const int rbase = rb * 16 + (lane >> 4) * 4;
        float* p = partial + (size_t)strip * NROWS + rbase;
        p[0] = acc.x;
        p[1] = acc.y;
        p[2] = acc.z;
        p[3] = acc.w;
    }
}

// ---------------------------------------------------------------------------
// Kernel B2: lse[r] = log( sum over 50 slots of partial[slot][r] )
// ---------------------------------------------------------------------------
__global__ __launch_bounds__(256) void k_reduce(
    const float* __restrict__ partial, float* __restrict__ lse)
{
    int r = blockIdx.x * 256 + threadIdx.x;
    if (r >= NROWS) return;
    float s = 0.f;
    #pragma unroll
    for (int k = 0; k < NSLOTS; ++k)
        s += partial[(size_t)k * NROWS + r];
    lse[r] = __logf(s);
}

// ---------------------------------------------------------------------------
// Kernel C: unchanged R9 structure (measured ~90 us @ 5.84 TB/s).
// Lanes own v4-columns; Wo in registers; 8-row groups.
// ---------------------------------------------------------------------------
__global__ __launch_bounds__(256) void k_write(
    const float* __restrict__ h_table, const float* __restrict__ wo,
    const float* __restrict__ lse, float* __restrict__ out)
{
    const int tid = threadIdx.x;
    const int strip = blockIdx.x & (STRIPS - 1);
    const int chunk = blockIdx.x / STRIPS;
    const int v4 = strip * 256 + tid;
    const bool act = v4 < V4;
    const int r0 = chunk * ROWS_W;

    const f32x4* wo4 = reinterpret_cast<const f32x4*>(wo);
    f32x4 w[HID];
    #pragma unroll
    for (int j = 0; j < HID; ++j) {
        if (act) w[j] = wo4[j * V4 + v4];
        else     w[j] = (f32x4){0.f, 0.f, 0.f, 0.f};
    }

    f32x4* out4 = reinterpret_cast<f32x4*>(out);

    for (int rr = r0; rr < r0 + ROWS_W; rr += RGROUP) {
        f32x4 acc[RGROUP];
        #pragma unroll
        for (int i = 0; i < RGROUP; ++i) acc[i] = (f32x4){0.f, 0.f, 0.f, 0.f};

        #pragma unroll
        for (int q = 0; q < 4; ++q) {
            f32x4 h4[RGROUP];
            #pragma unroll
            for (int i = 0; i < RGROUP; ++i)
                h4[i] = *reinterpret_cast<const f32x4*>(h_table + (rr + i) * HID + q * 4);
            #pragma unroll
            for (int i = 0; i < RGROUP; ++i) {
                acc[i] += h4[i].x * w[q * 4 + 0];
                acc[i] += h4[i].y * w[q * 4 + 1];
                acc[i] += h4[i].z * w[q * 4 + 2];
                acc[i] += h4[i].w * w[q * 4 + 3];
            }
        }

        const f32x4 ls0 = *reinterpret_cast<const f32x4*>(lse + rr);
        const f32x4 ls1 = *reinterpret_cast<const f32x4*>(lse + rr + 4);

        if (act) {
            #pragma unroll
            for (int i = 0; i < RGROUP; ++i) {
                float l = (i < 4) ? ls0[i & 3] : ls1[i & 3];
                f32x4 o = acc[i] - l;
                out4[(long)(rr + i) * V4 + v4] = o;
            }
        }
    }
}

extern "C" void kernel_launch(void* const* d_in, const int* in_sizes, int n_in,
                              void* d_out, int out_size, void* d_ws, size_t ws_size,
                              hipStream_t stream) {
    const int*   idx    = (const int*)d_in[0];
    const float* lookup = (const float*)d_in[1];
    const float* wx     = (const float*)d_in[2];
    const float* wh     = (const float*)d_in[3];
    const float* wo     = (const float*)d_in[4];
    const float* h0     = (const float*)d_in[5];
    float* out = (float*)d_out;

    float* h_table = (float*)d_ws;                    // 4096*16 f32      (256 KB)
    float* lse     = h_table + NROWS * HID;           // 4096 f32
    float* partial = lse + NROWS;                     // 50*4096 f32      (800 KB)
    short* a_frag  = (short*)(partial + NSLOTS * NROWS);   // 256*64*8 bf16 (256 KB)
    short* b_frag  = a_frag + NRB * 64 * 8;                // 2000*64*8 bf16 (2 MB)

    k_htable<<<NROWS / 256, 256, 0, stream>>>(idx, lookup, wx, wh, h0, h_table, a_frag);
    k_wpack<<<(NTILES * 64) / 256, 256, 0, stream>>>(wo, b_frag);
    k_expsum<<<(NRB * XSTRIPS) / 4, 256, 0, stream>>>(a_frag, b_frag, partial);
    k_reduce<<<NROWS / 256, 256, 0, stream>>>(partial, lse);
    k_write<<<STRIPS * CHUNKS, 256, 0, stream>>>(h_table, wo, lse, out);
}